// Round 1
// baseline (6103.307 us; speedup 1.0000x reference)
//
#include <hip/hip_runtime.h>

#define TT 512
#define HID 64

__device__ __forceinline__ float frcp(float x){ return __builtin_amdgcn_rcpf(x); }
__device__ __forceinline__ float frsq(float x){ return __builtin_amdgcn_rsqf(x); }
__device__ __forceinline__ float sigm(float x){
    // 1/(1+e^-x); e^-x -> inf gives rcp(inf)=0, no NaN
    return frcp(1.0f + __expf(-x));
}
__device__ __forceinline__ float tanh_fast(float x){
    x = fminf(15.0f, fmaxf(-15.0f, x));   // avoid inf/inf
    float e = __expf(2.0f * x);
    return (e - 1.0f) * frcp(e + 1.0f);
}

// One wave (64 lanes) per batch element. Lane i owns GRU rows {i, i+64, i+128}
// of w_ih/w_hh in VGPRs (231 regs) -> gh inner loop is 192 v_fmac_f32 with no
// memory traffic. Physics/LN computed redundantly on all lanes (wave-uniform).
// h round-trips a 64-float LDS buffer once per step (broadcast float4 reads).
__global__ __launch_bounds__(64, 1)
void kalman_kernel(const float* __restrict__ inputs,
                   const float* __restrict__ ln_gamma,
                   const float* __restrict__ ln_beta,
                   const float* __restrict__ w_ih,
                   const float* __restrict__ w_hh,
                   const float* __restrict__ b_ih,
                   const float* __restrict__ b_hh,
                   const float* __restrict__ fc_w,
                   const float* __restrict__ fc_b,
                   float* __restrict__ out)
{
    __shared__ float s_h[HID];
    __shared__ float s_K[40];
    __shared__ float s_fcwT[36 * 64];   // [j][k] = fc_w[k][j]

    const int lane = threadIdx.x;
    const int b    = blockIdx.x;

    // ---- weights -> VGPRs (amortized over 512 steps; L2-hot after 1st block) ----
    float whh[3][64];
#pragma unroll
    for (int s = 0; s < 3; ++s)
#pragma unroll
        for (int j = 0; j < 64; ++j)
            whh[s][j] = w_hh[(lane + 64 * s) * 64 + j];

    float wih[3][13];
#pragma unroll
    for (int s = 0; s < 3; ++s)
#pragma unroll
        for (int k = 0; k < 13; ++k)
            wih[s][k] = w_ih[(lane + 64 * s) * 13 + k];

    const float bih0 = b_ih[lane], bih1 = b_ih[lane + 64], bih2 = b_ih[lane + 128];
    const float bhh0 = b_hh[lane], bhh1 = b_hh[lane + 64], bhh2 = b_hh[lane + 128];

    float gam[13], bet[13];
#pragma unroll
    for (int k = 0; k < 13; ++k) { gam[k] = ln_gamma[k]; bet[k] = ln_beta[k]; }

    const int   kl  = (lane < 36) ? lane : 0;
    const float fcb = fc_b[kl];

    // stage fc_w transposed: s_fcwT[j*36+k] = fc_w[k*64+j] (coalesced loads)
#pragma unroll
    for (int it = 0; it < 36; ++it)
        s_fcwT[lane * 36 + it] = fc_w[it * 64 + lane];
    __syncthreads();

    // ---- state ----
    float pos0 = 0, pos1 = 0, pos2 = 0, vel0 = 0, vel1 = 0, vel2 = 0;
    float q0 = 1.0f, q1 = 0, q2 = 0, q3 = 0;
    float hme = 0.0f;            // h[lane]
    float hall[64];              // full h vector, refreshed each step
#pragma unroll
    for (int j = 0; j < 64; ++j) hall[j] = 0.0f;

    const float* ip = inputs + (size_t)b * TT * 9;
    float*       op = out    + (size_t)b * TT * 10;

    float cur[9];
#pragma unroll
    for (int k = 0; k < 9; ++k) cur[k] = ip[k];

    for (int t = 0; t < TT; ++t) {
        // software prefetch next step's input (hides global latency at 1 wave/SIMD)
        const int tn = (t < TT - 1) ? (t + 1) : t;
        float nxt[9];
#pragma unroll
        for (int k = 0; k < 9; ++k) nxt[k] = ip[(size_t)tn * 9 + k];

        const float ax = cur[0], ay = cur[1], az = cur[2];
        const float gx = cur[3], gy = cur[4], gz = cur[5];
        const float mx = cur[6], my = cur[7], mz = cur[8];

        // dq = normalize(1, gyro*dt/2)
        const float hx = gx * 0.005f, hy = gy * 0.005f, hz = gz * 0.005f;
        const float dn = frsq(1.0f + hx * hx + hy * hy + hz * hz);
        const float dw = dn, dx = hx * dn, dy = hy * dn, dz = hz * dn;

        // q_pred = normalize(q * dq)
        float qpw = q0 * dw - q1 * dx - q2 * dy - q3 * dz;
        float qpx = q0 * dx + q1 * dw + q2 * dz - q3 * dy;
        float qpy = q0 * dy - q1 * dz + q2 * dw + q3 * dx;
        float qpz = q0 * dz + q1 * dy - q2 * dx + q3 * dw;
        const float pn = frsq(qpw * qpw + qpx * qpx + qpy * qpy + qpz * qpz);
        qpw *= pn; qpx *= pn; qpy *= pn; qpz *= pn;

        // accel_world = R(q) @ accel - g   (old q!)
        const float r00 = 1.0f - 2.0f * (q2 * q2 + q3 * q3);
        const float r01 = 2.0f * (q1 * q2 - q3 * q0);
        const float r02 = 2.0f * (q1 * q3 + q2 * q0);
        const float r10 = 2.0f * (q1 * q2 + q3 * q0);
        const float r11 = 1.0f - 2.0f * (q1 * q1 + q3 * q3);
        const float r12 = 2.0f * (q2 * q3 - q1 * q0);
        const float r20 = 2.0f * (q1 * q3 - q2 * q0);
        const float r21 = 2.0f * (q2 * q3 + q1 * q0);
        const float r22 = 1.0f - 2.0f * (q1 * q1 + q2 * q2);
        const float awx = r00 * ax + r01 * ay + r02 * az;
        const float awy = r10 * ax + r11 * ay + r12 * az;
        const float awz = r20 * ax + r21 * ay + r22 * az - 9.81f;

        const float vpx = vel0 + awx * 0.01f;
        const float vpy = vel1 + awy * 0.01f;
        const float vpz = vel2 + awz * 0.01f;
        const float ppx = pos0 + vel0 * 0.01f + awx * 5e-5f;
        const float ppy = pos1 + vel1 * 0.01f + awy * 5e-5f;
        const float ppz = pos2 + vel2 * 0.01f + awz * 5e-5f;

        // rows 0,2 of R(q_pred) for the two inverse rotations
        const float s00 = 1.0f - 2.0f * (qpy * qpy + qpz * qpz);
        const float s01 = 2.0f * (qpx * qpy - qpz * qpw);
        const float s02 = 2.0f * (qpx * qpz + qpy * qpw);
        const float s20 = 2.0f * (qpx * qpz - qpy * qpw);
        const float s21 = 2.0f * (qpy * qpz + qpx * qpw);
        const float s22 = 1.0f - 2.0f * (qpx * qpx + qpy * qpy);
        const float gbx = 9.81f * s20, gby = 9.81f * s21, gbz = 9.81f * s22;
        const float mbx = 20.0f * s00 - 40.0f * s20;
        const float mby = 20.0f * s01 - 40.0f * s21;
        const float mbz = 20.0f * s02 - 40.0f * s22;

        float inn[6];
        inn[0] = mx - mbx; inn[1] = my - mby; inn[2] = mz - mbz;
        inn[3] = ax - gbx; inn[4] = ay - gby; inn[5] = az - gbz;

        float gin[13];
        gin[0] = inn[0]; gin[1] = inn[1]; gin[2] = inn[2];
        gin[3] = inn[3]; gin[4] = inn[4]; gin[5] = inn[5];
        gin[6] = vpx; gin[7] = vpy; gin[8] = vpz;
        gin[9] = qpw; gin[10] = qpx; gin[11] = qpy; gin[12] = qpz;

        // LayerNorm(13)
        float mu = 0.0f;
#pragma unroll
        for (int k = 0; k < 13; ++k) mu += gin[k];
        mu *= (1.0f / 13.0f);
        float var = 0.0f;
#pragma unroll
        for (int k = 0; k < 13; ++k) { const float d = gin[k] - mu; var += d * d; }
        var *= (1.0f / 13.0f);
        const float sc = frsq(var + 1e-5f);
        float gn[13];
#pragma unroll
        for (int k = 0; k < 13; ++k) gn[k] = (gin[k] - mu) * sc * gam[k] + bet[k];

        // gi = gn @ w_ih.T + b_ih (lane's 3 rows)
        float gi0 = bih0, gi1 = bih1, gi2 = bih2;
#pragma unroll
        for (int k = 0; k < 13; ++k) {
            gi0 += wih[0][k] * gn[k];
            gi1 += wih[1][k] * gn[k];
            gi2 += wih[2][k] * gn[k];
        }
        // gh = h @ w_hh.T + b_hh  — the hot loop: 192 v_fmac, all-register
        float gh0 = bhh0, gh1 = bhh1, gh2 = bhh2;
#pragma unroll
        for (int j = 0; j < 64; ++j) {
            gh0 += whh[0][j] * hall[j];
            gh1 += whh[1][j] * hall[j];
            gh2 += whh[2][j] * hall[j];
        }
        const float r = sigm(gi0 + gh0);
        const float z = sigm(gi1 + gh1);
        const float n = tanh_fast(gi2 + r * gh2);
        const float hnew = (1.0f - z) * n + z * hme;
        hme = hnew;

        __syncthreads();            // protect prior-step s_h/s_K readers
        s_h[lane] = hnew;
        __syncthreads();
#pragma unroll
        for (int j = 0; j < 64; j += 4) {
            const float4 h4 = *(const float4*)&s_h[j];   // broadcast, conflict-free
            hall[j] = h4.x; hall[j + 1] = h4.y; hall[j + 2] = h4.z; hall[j + 3] = h4.w;
        }

        // K[k] = fc_b[k] + sum_j fc_w[k][j] * h_new[j]   (lanes 0..35)
        float Kv = fcb;
#pragma unroll
        for (int j = 0; j < 64; ++j) Kv += s_fcwT[j * 36 + kl] * hall[j];
        if (lane < 36) s_K[lane] = Kv;
        __syncthreads();

        // corr = K(6x6) @ innovation  (redundant on all lanes, broadcast reads)
        float c0 = 0, c1 = 0, c2 = 0, c3 = 0, c4 = 0, c5 = 0;
#pragma unroll
        for (int j = 0; j < 6; ++j) {
            c0 += s_K[0 * 6 + j] * inn[j];
            c1 += s_K[1 * 6 + j] * inn[j];
            c2 += s_K[2 * 6 + j] * inn[j];
            c3 += s_K[3 * 6 + j] * inn[j];
            c4 += s_K[4 * 6 + j] * inn[j];
            c5 += s_K[5 * 6 + j] * inn[j];
        }

        pos0 = ppx + c0; pos1 = ppy + c1; pos2 = ppz + c2;
        vel0 = vpx + c3; vel1 = vpy + c4; vel2 = vpz + c5;
        q0 = qpw; q1 = qpx; q2 = qpy; q3 = qpz;

        // store x_new: lanes 0..9 write one coalesced 40B chunk
        const float val =
            lane == 0 ? pos0 : lane == 1 ? pos1 : lane == 2 ? pos2 :
            lane == 3 ? vel0 : lane == 4 ? vel1 : lane == 5 ? vel2 :
            lane == 6 ? q0   : lane == 7 ? q1   : lane == 8 ? q2   : q3;
        if (lane < 10) op[(size_t)t * 10 + lane] = val;

#pragma unroll
        for (int k = 0; k < 9; ++k) cur[k] = nxt[k];
    }
}

extern "C" void kernel_launch(void* const* d_in, const int* in_sizes, int n_in,
                              void* d_out, int out_size, void* d_ws, size_t ws_size,
                              hipStream_t stream) {
    const float* inputs   = (const float*)d_in[0];
    const float* ln_gamma = (const float*)d_in[1];
    const float* ln_beta  = (const float*)d_in[2];
    const float* w_ih     = (const float*)d_in[3];
    const float* w_hh     = (const float*)d_in[4];
    const float* b_ih     = (const float*)d_in[5];
    const float* b_hh     = (const float*)d_in[6];
    const float* fc_w     = (const float*)d_in[7];
    const float* fc_b     = (const float*)d_in[8];
    float* out = (float*)d_out;

    const int B = in_sizes[0] / (TT * 9);
    kalman_kernel<<<dim3(B), dim3(64), 0, stream>>>(
        inputs, ln_gamma, ln_beta, w_ih, w_hh, b_ih, b_hh, fc_w, fc_b, out);
}

// Round 2
// 3701.321 us; speedup vs baseline: 1.6490x; 1.6490x over previous
//
#include <hip/hip_runtime.h>

#define TT 512

typedef float vf2 __attribute__((ext_vector_type(2)));

__device__ __forceinline__ float frcp(float x){ return __builtin_amdgcn_rcpf(x); }
__device__ __forceinline__ float frsq(float x){ return __builtin_amdgcn_rsqf(x); }
__device__ __forceinline__ float sigm(float x){ return frcp(1.0f + __expf(-x)); }
__device__ __forceinline__ float tanh_fast(float x){
    x = fminf(15.0f, fmaxf(-15.0f, x));
    float e = __expf(2.0f * x);
    return (e - 1.0f) * frcp(e + 1.0f);
}
__device__ __forceinline__ float uniform_f(float x){
    return __int_as_float(__builtin_amdgcn_readfirstlane(__float_as_int(x)));
}

// One wave per batch element, everything register-resident:
//   lane i owns GRU rows {i,i+64,i+128} of w_hh (192 VGPR as 96 float2),
//   w_ih rows (39), fc_w row i%36 (64 VGPR as 32 float2), h[64] (32 float2).
// Only h (64 f) and K (36 f) round-trip LDS, all-broadcast reads.
// float2 FMAs -> v_pk_fma_f32 (full rate): gh loop = 96 instr, K = 32.
// ~415 VGPR demand: fits the 512 budget with no spill (1 wave/SIMD by design).
__global__ __launch_bounds__(64, 1)
void kalman_kernel(const float* __restrict__ inputs,
                   const float* __restrict__ ln_gamma,
                   const float* __restrict__ ln_beta,
                   const float* __restrict__ w_ih,
                   const float* __restrict__ w_hh,
                   const float* __restrict__ b_ih,
                   const float* __restrict__ b_hh,
                   const float* __restrict__ fc_w,
                   const float* __restrict__ fc_b,
                   float* __restrict__ out)
{
    __shared__ float s_h[64];
    __shared__ float s_K[40];

    const int lane = threadIdx.x;
    const int b    = blockIdx.x;

    // ---- preamble: pin weights in VGPRs (one-time, L2/L3-hot after first blocks) ----
    vf2 whh2[3][32];
#pragma unroll
    for (int s = 0; s < 3; ++s) {
        const float4* rp = (const float4*)(w_hh + (size_t)(lane + 64 * s) * 64);
#pragma unroll
        for (int m = 0; m < 16; ++m) {
            const float4 t = rp[m];
            whh2[s][2 * m]     = vf2{t.x, t.y};
            whh2[s][2 * m + 1] = vf2{t.z, t.w};
        }
    }

    float wih[3][13];
#pragma unroll
    for (int s = 0; s < 3; ++s)
#pragma unroll
        for (int k = 0; k < 13; ++k)
            wih[s][k] = w_ih[(lane + 64 * s) * 13 + k];

    const int kl = (lane < 36) ? lane : (lane - 36);   // lanes >=36 duplicate rows 0..27
    vf2 fc2[32];
    {
        const float4* rp = (const float4*)(fc_w + (size_t)kl * 64);
#pragma unroll
        for (int m = 0; m < 16; ++m) {
            const float4 t = rp[m];
            fc2[2 * m]     = vf2{t.x, t.y};
            fc2[2 * m + 1] = vf2{t.z, t.w};
        }
    }
    const float fcb  = fc_b[kl];
    const float bih0 = b_ih[lane], bih1 = b_ih[lane + 64], bih2 = b_ih[lane + 128];
    const float bhh0 = b_hh[lane], bhh1 = b_hh[lane + 64], bhh2 = b_hh[lane + 128];

    // LayerNorm params are wave-uniform -> force into SGPRs (free VALU operands)
    float gam[13], bet[13];
#pragma unroll
    for (int k = 0; k < 13; ++k) {
        gam[k] = uniform_f(ln_gamma[k]);
        bet[k] = uniform_f(ln_beta[k]);
    }

    // ---- state ----
    float pos0 = 0, pos1 = 0, pos2 = 0, vel0 = 0, vel1 = 0, vel2 = 0;
    float q0 = 1.0f, q1 = 0, q2 = 0, q3 = 0;
    float hme = 0.0f;
    vf2 h2[32];
#pragma unroll
    for (int m = 0; m < 32; ++m) h2[m] = vf2{0.0f, 0.0f};

    const float* ip = inputs + (size_t)b * TT * 9;
    float*       op = out    + (size_t)b * TT * 10;

    float cur[9];
#pragma unroll
    for (int k = 0; k < 9; ++k) cur[k] = ip[k];

    for (int t = 0; t < TT; ++t) {
        // prefetch next step's input early: a full step (~1000 cyc) of slack
        const int tn = (t < TT - 1) ? (t + 1) : t;
        float nxt[9];
#pragma unroll
        for (int k = 0; k < 9; ++k) nxt[k] = ip[(size_t)tn * 9 + k];

        const float ax = cur[0], ay = cur[1], az = cur[2];
        const float gx = cur[3], gy = cur[4], gz = cur[5];
        const float mx = cur[6], my = cur[7], mz = cur[8];

        // dq = normalize(1, gyro*dt/2); q_pred = normalize(q*dq)
        const float hx = gx * 0.005f, hy = gy * 0.005f, hz = gz * 0.005f;
        const float dn = frsq(1.0f + hx * hx + hy * hy + hz * hz);
        const float dw = dn, dx = hx * dn, dy = hy * dn, dz = hz * dn;
        float qpw = q0 * dw - q1 * dx - q2 * dy - q3 * dz;
        float qpx = q0 * dx + q1 * dw + q2 * dz - q3 * dy;
        float qpy = q0 * dy - q1 * dz + q2 * dw + q3 * dx;
        float qpz = q0 * dz + q1 * dy - q2 * dx + q3 * dw;
        const float pn = frsq(qpw * qpw + qpx * qpx + qpy * qpy + qpz * qpz);
        qpw *= pn; qpx *= pn; qpy *= pn; qpz *= pn;

        // accel_world = R(q) @ accel - g   (old q)
        const float r00 = 1.0f - 2.0f * (q2 * q2 + q3 * q3);
        const float r01 = 2.0f * (q1 * q2 - q3 * q0);
        const float r02 = 2.0f * (q1 * q3 + q2 * q0);
        const float r10 = 2.0f * (q1 * q2 + q3 * q0);
        const float r11 = 1.0f - 2.0f * (q1 * q1 + q3 * q3);
        const float r12 = 2.0f * (q2 * q3 - q1 * q0);
        const float r20 = 2.0f * (q1 * q3 - q2 * q0);
        const float r21 = 2.0f * (q2 * q3 + q1 * q0);
        const float r22 = 1.0f - 2.0f * (q1 * q1 + q2 * q2);
        const float awx = r00 * ax + r01 * ay + r02 * az;
        const float awy = r10 * ax + r11 * ay + r12 * az;
        const float awz = r20 * ax + r21 * ay + r22 * az - 9.81f;

        const float vpx = vel0 + awx * 0.01f;
        const float vpy = vel1 + awy * 0.01f;
        const float vpz = vel2 + awz * 0.01f;
        const float ppx = pos0 + vel0 * 0.01f + awx * 5e-5f;
        const float ppy = pos1 + vel1 * 0.01f + awy * 5e-5f;
        const float ppz = pos2 + vel2 * 0.01f + awz * 5e-5f;

        // rows 0,2 of R(q_pred) for the inverse rotations
        const float s00 = 1.0f - 2.0f * (qpy * qpy + qpz * qpz);
        const float s01 = 2.0f * (qpx * qpy - qpz * qpw);
        const float s02 = 2.0f * (qpx * qpz + qpy * qpw);
        const float s20 = 2.0f * (qpx * qpz - qpy * qpw);
        const float s21 = 2.0f * (qpy * qpz + qpx * qpw);
        const float s22 = 1.0f - 2.0f * (qpx * qpx + qpy * qpy);
        const float gbx = 9.81f * s20, gby = 9.81f * s21, gbz = 9.81f * s22;
        const float mbx = 20.0f * s00 - 40.0f * s20;
        const float mby = 20.0f * s01 - 40.0f * s21;
        const float mbz = 20.0f * s02 - 40.0f * s22;

        float inn[6];
        inn[0] = mx - mbx; inn[1] = my - mby; inn[2] = mz - mbz;
        inn[3] = ax - gbx; inn[4] = ay - gby; inn[5] = az - gbz;

        float gin[13];
        gin[0] = inn[0]; gin[1] = inn[1]; gin[2] = inn[2];
        gin[3] = inn[3]; gin[4] = inn[4]; gin[5] = inn[5];
        gin[6] = vpx; gin[7] = vpy; gin[8] = vpz;
        gin[9] = qpw; gin[10] = qpx; gin[11] = qpy; gin[12] = qpz;

        // LayerNorm(13)
        float mu = 0.0f;
#pragma unroll
        for (int k = 0; k < 13; ++k) mu += gin[k];
        mu *= (1.0f / 13.0f);
        float var = 0.0f;
#pragma unroll
        for (int k = 0; k < 13; ++k) { const float d = gin[k] - mu; var += d * d; }
        var *= (1.0f / 13.0f);
        const float sc = frsq(var + 1e-5f);

        // gi = LN(gin) @ w_ih.T + b_ih
        float gi0 = bih0, gi1 = bih1, gi2 = bih2;
#pragma unroll
        for (int k = 0; k < 13; ++k) {
            const float gn = (gin[k] - mu) * sc * gam[k] + bet[k];
            gi0 = fmaf(wih[0][k], gn, gi0);
            gi1 = fmaf(wih[1][k], gn, gi1);
            gi2 = fmaf(wih[2][k], gn, gi2);
        }

        // gh = h @ w_hh.T + b_hh  — 96 v_pk_fma_f32, all-register
        vf2 a0 = vf2{bhh0, 0.0f}, a1 = vf2{bhh1, 0.0f}, a2 = vf2{bhh2, 0.0f};
#pragma unroll
        for (int m = 0; m < 32; ++m) {
            a0 = __builtin_elementwise_fma(whh2[0][m], h2[m], a0);
            a1 = __builtin_elementwise_fma(whh2[1][m], h2[m], a1);
            a2 = __builtin_elementwise_fma(whh2[2][m], h2[m], a2);
        }
        const float gh0 = a0.x + a0.y, gh1 = a1.x + a1.y, gh2 = a2.x + a2.y;

        const float r = sigm(gi0 + gh0);
        const float z = sigm(gi1 + gh1);
        const float n = tanh_fast(gi2 + r * gh2);
        const float hnew = (1.0f - z) * n + z * hme;
        hme = hnew;

        // exchange h through LDS (single wave: barrier is just a waitcnt)
        __syncthreads();
        s_h[lane] = hnew;
        __syncthreads();
#pragma unroll
        for (int m = 0; m < 16; ++m) {
            const float4 t = *(const float4*)&s_h[4 * m];   // broadcast read
            h2[2 * m]     = vf2{t.x, t.y};
            h2[2 * m + 1] = vf2{t.z, t.w};
        }

        // K row (lanes 0..35): fc_b + fc_row . h_new — 32 v_pk_fma_f32
        vf2 ak = vf2{fcb, 0.0f};
#pragma unroll
        for (int m = 0; m < 32; ++m)
            ak = __builtin_elementwise_fma(fc2[m], h2[m], ak);
        if (lane < 36) s_K[lane] = ak.x + ak.y;
        __syncthreads();

        // corr = K(6x6) @ innovation (broadcast float4 reads, redundant on all lanes)
        float kk[36];
#pragma unroll
        for (int m = 0; m < 9; ++m) {
            const float4 t = *(const float4*)&s_K[4 * m];
            kk[4 * m] = t.x; kk[4 * m + 1] = t.y; kk[4 * m + 2] = t.z; kk[4 * m + 3] = t.w;
        }
        float c0 = 0, c1 = 0, c2 = 0, c3 = 0, c4 = 0, c5 = 0;
#pragma unroll
        for (int j = 0; j < 6; ++j) {
            c0 = fmaf(kk[0 * 6 + j], inn[j], c0);
            c1 = fmaf(kk[1 * 6 + j], inn[j], c1);
            c2 = fmaf(kk[2 * 6 + j], inn[j], c2);
            c3 = fmaf(kk[3 * 6 + j], inn[j], c3);
            c4 = fmaf(kk[4 * 6 + j], inn[j], c4);
            c5 = fmaf(kk[5 * 6 + j], inn[j], c5);
        }

        pos0 = ppx + c0; pos1 = ppy + c1; pos2 = ppz + c2;
        vel0 = vpx + c3; vel1 = vpy + c4; vel2 = vpz + c5;
        q0 = qpw; q1 = qpx; q2 = qpy; q3 = qpz;

        const float val =
            lane == 0 ? pos0 : lane == 1 ? pos1 : lane == 2 ? pos2 :
            lane == 3 ? vel0 : lane == 4 ? vel1 : lane == 5 ? vel2 :
            lane == 6 ? q0   : lane == 7 ? q1   : lane == 8 ? q2   : q3;
        if (lane < 10) op[(size_t)t * 10 + lane] = val;

#pragma unroll
        for (int k = 0; k < 9; ++k) cur[k] = nxt[k];
    }
}

extern "C" void kernel_launch(void* const* d_in, const int* in_sizes, int n_in,
                              void* d_out, int out_size, void* d_ws, size_t ws_size,
                              hipStream_t stream) {
    const float* inputs   = (const float*)d_in[0];
    const float* ln_gamma = (const float*)d_in[1];
    const float* ln_beta  = (const float*)d_in[2];
    const float* w_ih     = (const float*)d_in[3];
    const float* w_hh     = (const float*)d_in[4];
    const float* b_ih     = (const float*)d_in[5];
    const float* b_hh     = (const float*)d_in[6];
    const float* fc_w     = (const float*)d_in[7];
    const float* fc_b     = (const float*)d_in[8];
    float* out = (float*)d_out;

    const int B = in_sizes[0] / (TT * 9);
    kalman_kernel<<<dim3(B), dim3(64), 0, stream>>>(
        inputs, ln_gamma, ln_beta, w_ih, w_hh, b_ih, b_hh, fc_w, fc_b, out);
}

// Round 4
// 2241.056 us; speedup vs baseline: 2.7234x; 1.6516x over previous
//
#include <hip/hip_runtime.h>

#define TT 512

typedef _Float16 h2_t __attribute__((ext_vector_type(2)));

__device__ __forceinline__ float frcp(float x){ return __builtin_amdgcn_rcpf(x); }
__device__ __forceinline__ float frsq(float x){ return __builtin_amdgcn_rsqf(x); }
__device__ __forceinline__ float sigm(float x){ return frcp(1.0f + __expf(-x)); }
__device__ __forceinline__ float tanh_fast(float x){
    x = fminf(15.0f, fmaxf(-15.0f, x));
    float e = __expf(2.0f * x);
    return (e - 1.0f) * frcp(e + 1.0f);
}
__device__ __forceinline__ float uniform_f(float x){
    return __int_as_float(__builtin_amdgcn_readfirstlane(__float_as_int(x)));
}
__device__ __forceinline__ float fdot2(h2_t a, h2_t b, float c){
    return __builtin_amdgcn_fdot2(a, b, c, false);
}
__device__ __forceinline__ h2_t bc_h2(float x){ return __builtin_bit_cast(h2_t, x); }
__device__ __forceinline__ h2_t pk16(float a, float b){
    return __builtin_bit_cast(h2_t, __builtin_amdgcn_cvt_pkrtz(a, b));
}

// One wave per batch element. f16 weights + v_dot2_f32_f16 (f32 accumulate)
// halve the register footprint vs fp32: whh 96 + fc 32 + wih 21 + h 32 +
// state/temps ~70 <= 256 arch VGPRs -> NO AGPR spill churn and 2 waves/SIMD
// (launch_bounds(64,2)) so latency is hidden by a co-resident wave.
// h round-trips LDS as f16 (RTN cvt once per lane per step). All state,
// physics, LayerNorm, activations, K and corrections remain fp32.
__global__ __launch_bounds__(64, 2)
void kalman_kernel(const float* __restrict__ inputs,
                   const float* __restrict__ ln_gamma,
                   const float* __restrict__ ln_beta,
                   const float* __restrict__ w_ih,
                   const float* __restrict__ w_hh,
                   const float* __restrict__ b_ih,
                   const float* __restrict__ b_hh,
                   const float* __restrict__ fc_w,
                   const float* __restrict__ fc_b,
                   float* __restrict__ out)
{
    __shared__ _Float16 s_h[64];     // 128 B
    __shared__ float    s_K[36];

    const int lane = threadIdx.x;
    const int b    = blockIdx.x;

    // ---- preamble: weights -> f16 VGPRs (RTN scalar casts; one-time cost) ----
    h2_t whh2[3][32];
#pragma unroll
    for (int s = 0; s < 3; ++s) {
        const float* rp = w_hh + (size_t)(lane + 64 * s) * 64;
#pragma unroll
        for (int m = 0; m < 32; ++m)
            whh2[s][m] = h2_t{(_Float16)rp[2 * m], (_Float16)rp[2 * m + 1]};
    }

    h2_t wih2[3][7];
#pragma unroll
    for (int s = 0; s < 3; ++s) {
        const float* rp = w_ih + (size_t)(lane + 64 * s) * 13;
#pragma unroll
        for (int m = 0; m < 6; ++m)
            wih2[s][m] = h2_t{(_Float16)rp[2 * m], (_Float16)rp[2 * m + 1]};
        wih2[s][6] = h2_t{(_Float16)rp[12], (_Float16)0.0f};
    }

    const int kl = (lane < 36) ? lane : (lane - 36);
    h2_t fc2[32];
    {
        const float* rp = fc_w + (size_t)kl * 64;
#pragma unroll
        for (int m = 0; m < 32; ++m)
            fc2[m] = h2_t{(_Float16)rp[2 * m], (_Float16)rp[2 * m + 1]};
    }
    const float fcb  = fc_b[kl];
    const float bih0 = b_ih[lane], bih1 = b_ih[lane + 64], bih2 = b_ih[lane + 128];
    const float bhh0 = b_hh[lane], bhh1 = b_hh[lane + 64], bhh2 = b_hh[lane + 128];

    // wave-uniform LN params -> SGPRs
    float gam[13], bet[13];
#pragma unroll
    for (int k = 0; k < 13; ++k) {
        gam[k] = uniform_f(ln_gamma[k]);
        bet[k] = uniform_f(ln_beta[k]);
    }

    // ---- state ----
    float pos0 = 0, pos1 = 0, pos2 = 0, vel0 = 0, vel1 = 0, vel2 = 0;
    float q0 = 1.0f, q1 = 0, q2 = 0, q3 = 0;
    float hme = 0.0f;                 // own h[lane], exact f32
    h2_t h2[32];                      // full h vector, f16 (dot inputs only)
#pragma unroll
    for (int m = 0; m < 32; ++m) h2[m] = h2_t{(_Float16)0.0f, (_Float16)0.0f};

    const float* ip = inputs + (size_t)b * TT * 9;
    float*       op = out    + (size_t)b * TT * 10;

    float cur[9];
#pragma unroll
    for (int k = 0; k < 9; ++k) cur[k] = ip[k];

    for (int t = 0; t < TT; ++t) {
        const int tn = (t < TT - 1) ? (t + 1) : t;
        float nxt[9];
#pragma unroll
        for (int k = 0; k < 9; ++k) nxt[k] = ip[(size_t)tn * 9 + k];

        const float ax = cur[0], ay = cur[1], az = cur[2];
        const float gx = cur[3], gy = cur[4], gz = cur[5];
        const float mx = cur[6], my = cur[7], mz = cur[8];

        // dq = normalize(1, gyro*dt/2); q_pred = normalize(q*dq)
        const float hx = gx * 0.005f, hy = gy * 0.005f, hz = gz * 0.005f;
        const float dn = frsq(1.0f + hx * hx + hy * hy + hz * hz);
        const float dw = dn, dx = hx * dn, dy = hy * dn, dz = hz * dn;
        float qpw = q0 * dw - q1 * dx - q2 * dy - q3 * dz;
        float qpx = q0 * dx + q1 * dw + q2 * dz - q3 * dy;
        float qpy = q0 * dy - q1 * dz + q2 * dw + q3 * dx;
        float qpz = q0 * dz + q1 * dy - q2 * dx + q3 * dw;
        const float pn = frsq(qpw * qpw + qpx * qpx + qpy * qpy + qpz * qpz);
        qpw *= pn; qpx *= pn; qpy *= pn; qpz *= pn;

        // accel_world = R(q) @ accel - g   (old q)
        const float r00 = 1.0f - 2.0f * (q2 * q2 + q3 * q3);
        const float r01 = 2.0f * (q1 * q2 - q3 * q0);
        const float r02 = 2.0f * (q1 * q3 + q2 * q0);
        const float r10 = 2.0f * (q1 * q2 + q3 * q0);
        const float r11 = 1.0f - 2.0f * (q1 * q1 + q3 * q3);
        const float r12 = 2.0f * (q2 * q3 - q1 * q0);
        const float r20 = 2.0f * (q1 * q3 - q2 * q0);
        const float r21 = 2.0f * (q2 * q3 + q1 * q0);
        const float r22 = 1.0f - 2.0f * (q1 * q1 + q2 * q2);
        const float awx = r00 * ax + r01 * ay + r02 * az;
        const float awy = r10 * ax + r11 * ay + r12 * az;
        const float awz = r20 * ax + r21 * ay + r22 * az - 9.81f;

        const float vpx = vel0 + awx * 0.01f;
        const float vpy = vel1 + awy * 0.01f;
        const float vpz = vel2 + awz * 0.01f;
        const float ppx = pos0 + vel0 * 0.01f + awx * 5e-5f;
        const float ppy = pos1 + vel1 * 0.01f + awy * 5e-5f;
        const float ppz = pos2 + vel2 * 0.01f + awz * 5e-5f;

        // rows 0,2 of R(q_pred)
        const float s00 = 1.0f - 2.0f * (qpy * qpy + qpz * qpz);
        const float s01 = 2.0f * (qpx * qpy - qpz * qpw);
        const float s02 = 2.0f * (qpx * qpz + qpy * qpw);
        const float s20 = 2.0f * (qpx * qpz - qpy * qpw);
        const float s21 = 2.0f * (qpy * qpz + qpx * qpw);
        const float s22 = 1.0f - 2.0f * (qpx * qpx + qpy * qpy);
        const float gbx = 9.81f * s20, gby = 9.81f * s21, gbz = 9.81f * s22;
        const float mbx = 20.0f * s00 - 40.0f * s20;
        const float mby = 20.0f * s01 - 40.0f * s21;
        const float mbz = 20.0f * s02 - 40.0f * s22;

        float inn[6];
        inn[0] = mx - mbx; inn[1] = my - mby; inn[2] = mz - mbz;
        inn[3] = ax - gbx; inn[4] = ay - gby; inn[5] = az - gbz;

        float gin[13];
        gin[0] = inn[0]; gin[1] = inn[1]; gin[2] = inn[2];
        gin[3] = inn[3]; gin[4] = inn[4]; gin[5] = inn[5];
        gin[6] = vpx; gin[7] = vpy; gin[8] = vpz;
        gin[9] = qpw; gin[10] = qpx; gin[11] = qpy; gin[12] = qpz;

        // LayerNorm(13), f32
        float mu = 0.0f;
#pragma unroll
        for (int k = 0; k < 13; ++k) mu += gin[k];
        mu *= (1.0f / 13.0f);
        float var = 0.0f;
#pragma unroll
        for (int k = 0; k < 13; ++k) { const float d = gin[k] - mu; var += d * d; }
        var *= (1.0f / 13.0f);
        const float sc = frsq(var + 1e-5f);
        float gn[13];
#pragma unroll
        for (int k = 0; k < 13; ++k) gn[k] = (gin[k] - mu) * sc * gam[k] + bet[k];

        // pack LN output to f16 pairs (7 cvt_pkrtz)
        h2_t g2[7];
#pragma unroll
        for (int m = 0; m < 6; ++m)
            g2[m] = pk16(gn[2 * m], gn[2 * m + 1]);
        g2[6] = pk16(gn[12], 0.0f);

        // gi = LN(gin) @ w_ih.T + b_ih  — 21 v_dot2_f32_f16
        float gi0 = bih0, gi1 = bih1, gi2 = bih2;
#pragma unroll
        for (int m = 0; m < 7; ++m) {
            gi0 = fdot2(wih2[0][m], g2[m], gi0);
            gi1 = fdot2(wih2[1][m], g2[m], gi1);
            gi2 = fdot2(wih2[2][m], g2[m], gi2);
        }

        // gh = h @ w_hh.T + b_hh — 96 v_dot2_f32_f16, all-register, f32 acc
        float gh0 = bhh0, gh1 = bhh1, gh2 = bhh2;
#pragma unroll
        for (int m = 0; m < 32; ++m) {
            gh0 = fdot2(whh2[0][m], h2[m], gh0);
            gh1 = fdot2(whh2[1][m], h2[m], gh1);
            gh2 = fdot2(whh2[2][m], h2[m], gh2);
        }

        const float r = sigm(gi0 + gh0);
        const float z = sigm(gi1 + gh1);
        const float n = tanh_fast(gi2 + r * gh2);
        const float hnew = (1.0f - z) * n + z * hme;
        hme = hnew;

        // h exchange through LDS as f16 (RTN cast); single-wave block barrier
        __syncthreads();
        s_h[lane] = (_Float16)hnew;
        __syncthreads();
#pragma unroll
        for (int m = 0; m < 8; ++m) {
            const float4 tv = *(const float4*)&s_h[8 * m];   // 16B broadcast
            h2[4 * m]     = bc_h2(tv.x);
            h2[4 * m + 1] = bc_h2(tv.y);
            h2[4 * m + 2] = bc_h2(tv.z);
            h2[4 * m + 3] = bc_h2(tv.w);
        }

        // K row (lanes 0..35): fc_b + fc_row . h_new — 32 dot2, f32 acc
        float Kv = fcb;
#pragma unroll
        for (int m = 0; m < 32; ++m) Kv = fdot2(fc2[m], h2[m], Kv);
        if (lane < 36) s_K[lane] = Kv;
        __syncthreads();

        // corr = K(6x6) @ innovation — stream 9 float4, no kk[36] materialization
        float c[6] = {0, 0, 0, 0, 0, 0};
#pragma unroll
        for (int m = 0; m < 9; ++m) {
            const float4 tv = *(const float4*)&s_K[4 * m];
            const float tt[4] = {tv.x, tv.y, tv.z, tv.w};
#pragma unroll
            for (int l = 0; l < 4; ++l) {
                const int idx = 4 * m + l;
                c[idx / 6] = fmaf(tt[l], inn[idx % 6], c[idx / 6]);
            }
        }

        pos0 = ppx + c[0]; pos1 = ppy + c[1]; pos2 = ppz + c[2];
        vel0 = vpx + c[3]; vel1 = vpy + c[4]; vel2 = vpz + c[5];
        q0 = qpw; q1 = qpx; q2 = qpy; q3 = qpz;

        const float val =
            lane == 0 ? pos0 : lane == 1 ? pos1 : lane == 2 ? pos2 :
            lane == 3 ? vel0 : lane == 4 ? vel1 : lane == 5 ? vel2 :
            lane == 6 ? q0   : lane == 7 ? q1   : lane == 8 ? q2   : q3;
        if (lane < 10) op[(size_t)t * 10 + lane] = val;

#pragma unroll
        for (int k = 0; k < 9; ++k) cur[k] = nxt[k];
    }
}

extern "C" void kernel_launch(void* const* d_in, const int* in_sizes, int n_in,
                              void* d_out, int out_size, void* d_ws, size_t ws_size,
                              hipStream_t stream) {
    const float* inputs   = (const float*)d_in[0];
    const float* ln_gamma = (const float*)d_in[1];
    const float* ln_beta  = (const float*)d_in[2];
    const float* w_ih     = (const float*)d_in[3];
    const float* w_hh     = (const float*)d_in[4];
    const float* b_ih     = (const float*)d_in[5];
    const float* b_hh     = (const float*)d_in[6];
    const float* fc_w     = (const float*)d_in[7];
    const float* fc_b     = (const float*)d_in[8];
    float* out = (float*)d_out;

    const int B = in_sizes[0] / (TT * 9);
    kalman_kernel<<<dim3(B), dim3(64), 0, stream>>>(
        inputs, ln_gamma, ln_beta, w_ih, w_hh, b_ih, b_hh, fc_w, fc_b, out);
}

// Round 5
// 2050.328 us; speedup vs baseline: 2.9767x; 1.0930x over previous
//
#include <hip/hip_runtime.h>

#define TT 512

typedef _Float16 h2_t __attribute__((ext_vector_type(2)));

__device__ __forceinline__ float frcp(float x){ return __builtin_amdgcn_rcpf(x); }
__device__ __forceinline__ float frsq(float x){ return __builtin_amdgcn_rsqf(x); }
__device__ __forceinline__ float sigm(float x){ return frcp(1.0f + __expf(-x)); }
__device__ __forceinline__ float tanh_fast(float x){
    x = fminf(15.0f, fmaxf(-15.0f, x));
    float e = __expf(2.0f * x);
    return (e - 1.0f) * frcp(e + 1.0f);
}
__device__ __forceinline__ float uniform_f(float x){
    return __int_as_float(__builtin_amdgcn_readfirstlane(__float_as_int(x)));
}
__device__ __forceinline__ float fdot2(h2_t a, h2_t b, float c){
    return __builtin_amdgcn_fdot2(a, b, c, false);
}
__device__ __forceinline__ h2_t bc_h2(float x){ return __builtin_bit_cast(h2_t, x); }
__device__ __forceinline__ h2_t pk16(float a, float b){
    return __builtin_bit_cast(h2_t, __builtin_amdgcn_cvt_pkrtz(a, b));
}

// One wave per batch element, f16 weights in VGPRs + v_dot2_f32_f16.
// waves_per_eu(2,2): min AND max 2 waves/EU -> allocator budget is exactly
// 256 VGPRs. Demand ~230 fits, so the backend has no occupancy incentive to
// rematerialize/spill the pinned weights into the step loop (R4 pathology:
// launch_bounds(64,2) let it target 4 waves/EU = 128 VGPRs and it sank the
// weight loads back into the loop). 2 waves/SIMD co-resident hide latency.
__global__
__attribute__((amdgpu_flat_work_group_size(64, 64), amdgpu_waves_per_eu(2, 2)))
void kalman_kernel(const float* __restrict__ inputs,
                   const float* __restrict__ ln_gamma,
                   const float* __restrict__ ln_beta,
                   const float* __restrict__ w_ih,
                   const float* __restrict__ w_hh,
                   const float* __restrict__ b_ih,
                   const float* __restrict__ b_hh,
                   const float* __restrict__ fc_w,
                   const float* __restrict__ fc_b,
                   float* __restrict__ out)
{
    __shared__ _Float16 s_h[64];     // 128 B
    __shared__ float    s_K[36];

    const int lane = threadIdx.x;
    const int b    = blockIdx.x;

    // ---- preamble: weights -> f16 VGPRs (RTN scalar casts; one-time cost) ----
    h2_t whh2[3][32];
#pragma unroll
    for (int s = 0; s < 3; ++s) {
        const float* rp = w_hh + (size_t)(lane + 64 * s) * 64;
#pragma unroll
        for (int m = 0; m < 32; ++m)
            whh2[s][m] = h2_t{(_Float16)rp[2 * m], (_Float16)rp[2 * m + 1]};
    }

    h2_t wih2[3][7];
#pragma unroll
    for (int s = 0; s < 3; ++s) {
        const float* rp = w_ih + (size_t)(lane + 64 * s) * 13;
#pragma unroll
        for (int m = 0; m < 6; ++m)
            wih2[s][m] = h2_t{(_Float16)rp[2 * m], (_Float16)rp[2 * m + 1]};
        wih2[s][6] = h2_t{(_Float16)rp[12], (_Float16)0.0f};
    }

    const int kl = (lane < 36) ? lane : (lane - 36);
    h2_t fc2[32];
    {
        const float* rp = fc_w + (size_t)kl * 64;
#pragma unroll
        for (int m = 0; m < 32; ++m)
            fc2[m] = h2_t{(_Float16)rp[2 * m], (_Float16)rp[2 * m + 1]};
    }
    const float fcb  = fc_b[kl];
    const float bih0 = b_ih[lane], bih1 = b_ih[lane + 64], bih2 = b_ih[lane + 128];
    const float bhh0 = b_hh[lane], bhh1 = b_hh[lane + 64], bhh2 = b_hh[lane + 128];

    // wave-uniform LN params -> SGPRs (free VALU operands, zero VGPR cost)
    float gam[13], bet[13];
#pragma unroll
    for (int k = 0; k < 13; ++k) {
        gam[k] = uniform_f(ln_gamma[k]);
        bet[k] = uniform_f(ln_beta[k]);
    }

    // ---- state ----
    float pos0 = 0, pos1 = 0, pos2 = 0, vel0 = 0, vel1 = 0, vel2 = 0;
    float q0 = 1.0f, q1 = 0, q2 = 0, q3 = 0;
    float hme = 0.0f;                 // own h[lane], exact f32
    h2_t h2[32];                      // full h vector, f16 (dot inputs only)
#pragma unroll
    for (int m = 0; m < 32; ++m) h2[m] = h2_t{(_Float16)0.0f, (_Float16)0.0f};

    const float* ip = inputs + (size_t)b * TT * 9;
    float*       op = out    + (size_t)b * TT * 10;

    float cur[9];
#pragma unroll
    for (int k = 0; k < 9; ++k) cur[k] = ip[k];

    for (int t = 0; t < TT; ++t) {
        const int tn = (t < TT - 1) ? (t + 1) : t;
        float nxt[9];
#pragma unroll
        for (int k = 0; k < 9; ++k) nxt[k] = ip[(size_t)tn * 9 + k];

        const float ax = cur[0], ay = cur[1], az = cur[2];
        const float gx = cur[3], gy = cur[4], gz = cur[5];
        const float mx = cur[6], my = cur[7], mz = cur[8];

        // dq = normalize(1, gyro*dt/2); q_pred = normalize(q*dq)
        const float hx = gx * 0.005f, hy = gy * 0.005f, hz = gz * 0.005f;
        const float dn = frsq(1.0f + hx * hx + hy * hy + hz * hz);
        const float dw = dn, dx = hx * dn, dy = hy * dn, dz = hz * dn;
        float qpw = q0 * dw - q1 * dx - q2 * dy - q3 * dz;
        float qpx = q0 * dx + q1 * dw + q2 * dz - q3 * dy;
        float qpy = q0 * dy - q1 * dz + q2 * dw + q3 * dx;
        float qpz = q0 * dz + q1 * dy - q2 * dx + q3 * dw;
        const float pn = frsq(qpw * qpw + qpx * qpx + qpy * qpy + qpz * qpz);
        qpw *= pn; qpx *= pn; qpy *= pn; qpz *= pn;

        // accel_world = R(q) @ accel - g   (old q)
        const float r00 = 1.0f - 2.0f * (q2 * q2 + q3 * q3);
        const float r01 = 2.0f * (q1 * q2 - q3 * q0);
        const float r02 = 2.0f * (q1 * q3 + q2 * q0);
        const float r10 = 2.0f * (q1 * q2 + q3 * q0);
        const float r11 = 1.0f - 2.0f * (q1 * q1 + q3 * q3);
        const float r12 = 2.0f * (q2 * q3 - q1 * q0);
        const float r20 = 2.0f * (q1 * q3 - q2 * q0);
        const float r21 = 2.0f * (q2 * q3 + q1 * q0);
        const float r22 = 1.0f - 2.0f * (q1 * q1 + q2 * q2);
        const float awx = r00 * ax + r01 * ay + r02 * az;
        const float awy = r10 * ax + r11 * ay + r12 * az;
        const float awz = r20 * ax + r21 * ay + r22 * az - 9.81f;

        const float vpx = vel0 + awx * 0.01f;
        const float vpy = vel1 + awy * 0.01f;
        const float vpz = vel2 + awz * 0.01f;
        const float ppx = pos0 + vel0 * 0.01f + awx * 5e-5f;
        const float ppy = pos1 + vel1 * 0.01f + awy * 5e-5f;
        const float ppz = pos2 + vel2 * 0.01f + awz * 5e-5f;

        // rows 0,2 of R(q_pred)
        const float s00 = 1.0f - 2.0f * (qpy * qpy + qpz * qpz);
        const float s01 = 2.0f * (qpx * qpy - qpz * qpw);
        const float s02 = 2.0f * (qpx * qpz + qpy * qpw);
        const float s20 = 2.0f * (qpx * qpz - qpy * qpw);
        const float s21 = 2.0f * (qpy * qpz + qpx * qpw);
        const float s22 = 1.0f - 2.0f * (qpx * qpx + qpy * qpy);
        const float gbx = 9.81f * s20, gby = 9.81f * s21, gbz = 9.81f * s22;
        const float mbx = 20.0f * s00 - 40.0f * s20;
        const float mby = 20.0f * s01 - 40.0f * s21;
        const float mbz = 20.0f * s02 - 40.0f * s22;

        float inn[6];
        inn[0] = mx - mbx; inn[1] = my - mby; inn[2] = mz - mbz;
        inn[3] = ax - gbx; inn[4] = ay - gby; inn[5] = az - gbz;

        float gin[13];
        gin[0] = inn[0]; gin[1] = inn[1]; gin[2] = inn[2];
        gin[3] = inn[3]; gin[4] = inn[4]; gin[5] = inn[5];
        gin[6] = vpx; gin[7] = vpy; gin[8] = vpz;
        gin[9] = qpw; gin[10] = qpx; gin[11] = qpy; gin[12] = qpz;

        // LayerNorm(13), f32
        float mu = 0.0f;
#pragma unroll
        for (int k = 0; k < 13; ++k) mu += gin[k];
        mu *= (1.0f / 13.0f);
        float var = 0.0f;
#pragma unroll
        for (int k = 0; k < 13; ++k) { const float d = gin[k] - mu; var += d * d; }
        var *= (1.0f / 13.0f);
        const float sc = frsq(var + 1e-5f);

        // LN -> f16 pairs, fused (keeps live set small)
        h2_t g2[7];
#pragma unroll
        for (int m = 0; m < 6; ++m) {
            const float a = (gin[2 * m]     - mu) * sc * gam[2 * m]     + bet[2 * m];
            const float c = (gin[2 * m + 1] - mu) * sc * gam[2 * m + 1] + bet[2 * m + 1];
            g2[m] = pk16(a, c);
        }
        g2[6] = pk16((gin[12] - mu) * sc * gam[12] + bet[12], 0.0f);

        // gi = LN(gin) @ w_ih.T + b_ih  — 21 v_dot2_f32_f16
        float gi0 = bih0, gi1 = bih1, gi2 = bih2;
#pragma unroll
        for (int m = 0; m < 7; ++m) {
            gi0 = fdot2(wih2[0][m], g2[m], gi0);
            gi1 = fdot2(wih2[1][m], g2[m], gi1);
            gi2 = fdot2(wih2[2][m], g2[m], gi2);
        }

        // gh = h @ w_hh.T + b_hh — 96 v_dot2_f32_f16, all-register, f32 acc
        float gh0 = bhh0, gh1 = bhh1, gh2 = bhh2;
#pragma unroll
        for (int m = 0; m < 32; ++m) {
            gh0 = fdot2(whh2[0][m], h2[m], gh0);
            gh1 = fdot2(whh2[1][m], h2[m], gh1);
            gh2 = fdot2(whh2[2][m], h2[m], gh2);
        }

        const float r = sigm(gi0 + gh0);
        const float z = sigm(gi1 + gh1);
        const float n = tanh_fast(gi2 + r * gh2);
        const float hnew = (1.0f - z) * n + z * hme;
        hme = hnew;

        // h exchange through LDS as f16 (RTN cast); single-wave block barrier
        __syncthreads();
        s_h[lane] = (_Float16)hnew;
        __syncthreads();
#pragma unroll
        for (int m = 0; m < 8; ++m) {
            const float4 tv = *(const float4*)&s_h[8 * m];   // 16B broadcast
            h2[4 * m]     = bc_h2(tv.x);
            h2[4 * m + 1] = bc_h2(tv.y);
            h2[4 * m + 2] = bc_h2(tv.z);
            h2[4 * m + 3] = bc_h2(tv.w);
        }

        // K row (lanes 0..35): fc_b + fc_row . h_new — 32 dot2, f32 acc
        float Kv = fcb;
#pragma unroll
        for (int m = 0; m < 32; ++m) Kv = fdot2(fc2[m], h2[m], Kv);
        if (lane < 36) s_K[lane] = Kv;
        __syncthreads();

        // corr = K(6x6) @ innovation — stream 9 float4
        float c[6] = {0, 0, 0, 0, 0, 0};
#pragma unroll
        for (int m = 0; m < 9; ++m) {
            const float4 tv = *(const float4*)&s_K[4 * m];
            const float tt[4] = {tv.x, tv.y, tv.z, tv.w};
#pragma unroll
            for (int l = 0; l < 4; ++l) {
                const int idx = 4 * m + l;
                c[idx / 6] = fmaf(tt[l], inn[idx % 6], c[idx / 6]);
            }
        }

        pos0 = ppx + c[0]; pos1 = ppy + c[1]; pos2 = ppz + c[2];
        vel0 = vpx + c[3]; vel1 = vpy + c[4]; vel2 = vpz + c[5];
        q0 = qpw; q1 = qpx; q2 = qpy; q3 = qpz;

        const float val =
            lane == 0 ? pos0 : lane == 1 ? pos1 : lane == 2 ? pos2 :
            lane == 3 ? vel0 : lane == 4 ? vel1 : lane == 5 ? vel2 :
            lane == 6 ? q0   : lane == 7 ? q1   : lane == 8 ? q2   : q3;
        if (lane < 10) op[(size_t)t * 10 + lane] = val;

#pragma unroll
        for (int k = 0; k < 9; ++k) cur[k] = nxt[k];
    }
}

extern "C" void kernel_launch(void* const* d_in, const int* in_sizes, int n_in,
                              void* d_out, int out_size, void* d_ws, size_t ws_size,
                              hipStream_t stream) {
    const float* inputs   = (const float*)d_in[0];
    const float* ln_gamma = (const float*)d_in[1];
    const float* ln_beta  = (const float*)d_in[2];
    const float* w_ih     = (const float*)d_in[3];
    const float* w_hh     = (const float*)d_in[4];
    const float* b_ih     = (const float*)d_in[5];
    const float* b_hh     = (const float*)d_in[6];
    const float* fc_w     = (const float*)d_in[7];
    const float* fc_b     = (const float*)d_in[8];
    float* out = (float*)d_out;

    const int B = in_sizes[0] / (TT * 9);
    kalman_kernel<<<dim3(B), dim3(64), 0, stream>>>(
        inputs, ln_gamma, ln_beta, w_ih, w_hh, b_ih, b_hh, fc_w, fc_b, out);
}